// Round 1
// baseline (3659.757 us; speedup 1.0000x reference)
//
#include <hip/hip_runtime.h>
#include <hip/hip_bf16.h>

#define TT 32
#define DD 128
#define HH 256
#define VV 32000
#define ZZ 256
#define NT 500  // VV / 64 column tiles in out_gemm

typedef __attribute__((ext_vector_type(8))) short bf16x8;
typedef __attribute__((ext_vector_type(4))) float f32x4;

// ---------------- edges canonicalizer (bool-vs-int32 layout detect) ----------------
__global__ void edge_canon_k(const unsigned char* __restrict__ eb,
                             unsigned char* __restrict__ canon)
{
    __shared__ int flag;
    if (threadIdx.x == 0) flag = 0;
    __syncthreads();
    int acc = 0;
    for (int i = threadIdx.x; i < TT * DD; i += 256)
        if (i & 3) acc |= eb[i];
    if (acc) atomicOr(&flag, 1);
    __syncthreads();
    const bool is_i32 = (flag == 0);   // bytes at %4!=0 all zero => int32 little-endian 0/1
    for (int i = threadIdx.x; i < TT * DD; i += 256)
        canon[i] = is_i32 ? eb[4 * (size_t)i] : eb[i];
}

// ---------------- f32 -> bf16 conversion (W_out) ----------------
__global__ void conv_bf16(const float* __restrict__ src,
                          __hip_bfloat16* __restrict__ dst, int n)
{
    int stride = gridDim.x * blockDim.x;
    for (int i = blockIdx.x * blockDim.x + threadIdx.x; i * 4 < n; i += stride) {
        float4 v = ((const float4*)src)[i];
        dst[4 * i + 0] = __float2bfloat16(v.x);
        dst[4 * i + 1] = __float2bfloat16(v.y);
        dst[4 * i + 2] = __float2bfloat16(v.z);
        dst[4 * i + 3] = __float2bfloat16(v.w);
    }
}

// ---------------- one GRU step (branch-aware, child vs sibling per node) ----------------
// grid (8, 32) = (H/32 j-tiles, D/4 d-tiles), block 128 = 32 j x 4 d
__global__ __launch_bounds__(128) void gru_step(
    const int* __restrict__ nodes_t, const unsigned char* __restrict__ edges_t,
    const float* __restrict__ emb,
    const float* __restrict__ Wih_c, const float* __restrict__ Whh_c,
    const float* __restrict__ bih_c, const float* __restrict__ bhh_c,
    const float* __restrict__ Wih_s, const float* __restrict__ Whh_s,
    const float* __restrict__ bih_s, const float* __restrict__ bhh_s,
    const float* __restrict__ h_in, float* __restrict__ h_out,
    __hip_bfloat16* __restrict__ outs_t)
{
    const int jl = threadIdx.x & 31;
    const int dl = threadIdx.x >> 5;
    const int j  = blockIdx.x * 32 + jl;
    const int d  = blockIdx.y * 4 + dl;

    const int  tok = nodes_t[d];
    const bool e   = edges_t[d] != 0;
    const float* __restrict__ Wih = e ? Wih_c : Wih_s;
    const float* __restrict__ Whh = e ? Whh_c : Whh_s;
    const float* __restrict__ bih = e ? bih_c : bih_s;
    const float* __restrict__ bhh = e ? bhh_c : bhh_s;

    const float* __restrict__ xrow = emb + (size_t)tok * HH;
    const float* __restrict__ hrow = h_in + (size_t)d * HH;
    const float4* __restrict__ x4 = (const float4*)xrow;
    const float4* __restrict__ h4 = (const float4*)hrow;
    const float4* __restrict__ wir = (const float4*)(Wih + (size_t)j * HH);
    const float4* __restrict__ wiz = (const float4*)(Wih + (size_t)(j + HH) * HH);
    const float4* __restrict__ win = (const float4*)(Wih + (size_t)(j + 2 * HH) * HH);
    const float4* __restrict__ whr = (const float4*)(Whh + (size_t)j * HH);
    const float4* __restrict__ whz = (const float4*)(Whh + (size_t)(j + HH) * HH);
    const float4* __restrict__ whn = (const float4*)(Whh + (size_t)(j + 2 * HH) * HH);

    float sir = 0.f, siz = 0.f, sin_ = 0.f, shr = 0.f, shz = 0.f, shn = 0.f;
#pragma unroll 8
    for (int k = 0; k < HH / 4; ++k) {
        float4 xv = x4[k], hv = h4[k];
        float4 w0 = wir[k], w1 = wiz[k], w2 = win[k];
        float4 w3 = whr[k], w4 = whz[k], w5 = whn[k];
        sir  += xv.x * w0.x + xv.y * w0.y + xv.z * w0.z + xv.w * w0.w;
        siz  += xv.x * w1.x + xv.y * w1.y + xv.z * w1.z + xv.w * w1.w;
        sin_ += xv.x * w2.x + xv.y * w2.y + xv.z * w2.z + xv.w * w2.w;
        shr  += hv.x * w3.x + hv.y * w3.y + hv.z * w3.z + hv.w * w3.w;
        shz  += hv.x * w4.x + hv.y * w4.y + hv.z * w4.z + hv.w * w4.w;
        shn  += hv.x * w5.x + hv.y * w5.y + hv.z * w5.z + hv.w * w5.w;
    }
    float ir = sir + bih[j],            hr = shr + bhh[j];
    float iz = siz + bih[j + HH],       hz = shz + bhh[j + HH];
    float in_ = sin_ + bih[j + 2 * HH], hn = shn + bhh[j + 2 * HH];
    float r  = 1.f / (1.f + expf(-(ir + hr)));
    float zg = 1.f / (1.f + expf(-(iz + hz)));
    float n  = tanhf(in_ + r * hn);
    float hnew = (1.f - zg) * n + zg * hrow[j];
    h_out[(size_t)d * HH + j] = hnew;
    if (outs_t) outs_t[(size_t)d * HH + j] = __float2bfloat16(hnew);
}

// ---------------- latent head: mean, logv, z ----------------
__global__ __launch_bounds__(256) void latent_k(
    const float* __restrict__ hid, const float* __restrict__ W_mean,
    const float* __restrict__ b_mean, const float* __restrict__ W_logv,
    const float* __restrict__ b_logv, const float* __restrict__ eps,
    float* __restrict__ out_mean, float* __restrict__ out_logv,
    float* __restrict__ out_z)
{
    int idx = blockIdx.x * blockDim.x + threadIdx.x;  // D*Z = 32768
    int d = idx >> 8, zi = idx & 255;
    const float4* hv = (const float4*)(hid + (size_t)d * HH);
    const float4* wm = (const float4*)(W_mean + (size_t)zi * HH);
    const float4* wl = (const float4*)(W_logv + (size_t)zi * HH);
    float sm = 0.f, sl = 0.f;
#pragma unroll 8
    for (int k = 0; k < HH / 4; ++k) {
        float4 h4 = hv[k], m4 = wm[k], l4 = wl[k];
        sm += h4.x * m4.x + h4.y * m4.y + h4.z * m4.z + h4.w * m4.w;
        sl += h4.x * l4.x + h4.y * l4.y + h4.z * l4.z + h4.w * l4.w;
    }
    float mean = sm + b_mean[zi];
    float logv = sl + b_logv[zi];
    float zval = eps[idx] * expf(0.5f * logv) + mean;
    out_mean[idx] = mean;
    out_logv[idx] = logv;
    out_z[idx]    = zval;
}

// ---------------- h0 = z @ W_l2h.T + b ----------------
__global__ __launch_bounds__(256) void h0_k(
    const float* __restrict__ z, const float* __restrict__ W_l2h,
    const float* __restrict__ b_l2h, float* __restrict__ h0)
{
    int idx = blockIdx.x * blockDim.x + threadIdx.x;  // D*H = 32768
    int d = idx >> 8, j = idx & 255;
    const float4* zv = (const float4*)(z + (size_t)d * ZZ);
    const float4* wv = (const float4*)(W_l2h + (size_t)j * ZZ);
    float s = 0.f;
#pragma unroll 8
    for (int k = 0; k < ZZ / 4; ++k) {
        float4 a = zv[k], b = wv[k];
        s += a.x * b.x + a.y * b.y + a.z * b.z + a.w * b.w;
    }
    h0[idx] = s + b_l2h[j];
}

// ---------------- logits GEMM (bf16 MFMA) + fused partial max/sumexp ----------------
// grid (4096/64, 32000/64) block 256 (4 waves). Wave computes 16(M) x 64(N).
__global__ __launch_bounds__(256) void out_gemm(
    const __hip_bfloat16* __restrict__ A,   // [4096][256] decoder outs
    const __hip_bfloat16* __restrict__ B,   // [32000][256] W_out bf16
    const float* __restrict__ bias,         // [32000]
    float* __restrict__ out,                // [4096][32000] logits
    float* __restrict__ pm, float* __restrict__ ps)  // [4096][NT]
{
    const int wv   = threadIdx.x >> 6;
    const int lane = threadIdx.x & 63;
    const int g    = lane >> 4;
    const int c    = lane & 15;
    const int mrow = blockIdx.x * 64 + wv * 16;
    const int nb   = blockIdx.y * 64;

    f32x4 acc[4] = {{0,0,0,0},{0,0,0,0},{0,0,0,0},{0,0,0,0}};
    const __hip_bfloat16* arow = A + (size_t)(mrow + c) * HH + 8 * g;
    const __hip_bfloat16* b0 = B + (size_t)(nb +  0 + c) * HH + 8 * g;
    const __hip_bfloat16* b1 = B + (size_t)(nb + 16 + c) * HH + 8 * g;
    const __hip_bfloat16* b2 = B + (size_t)(nb + 32 + c) * HH + 8 * g;
    const __hip_bfloat16* b3 = B + (size_t)(nb + 48 + c) * HH + 8 * g;
#pragma unroll
    for (int k0 = 0; k0 < HH; k0 += 32) {
        bf16x8 a = *(const bf16x8*)(arow + k0);
        acc[0] = __builtin_amdgcn_mfma_f32_16x16x32_bf16(a, *(const bf16x8*)(b0 + k0), acc[0], 0, 0, 0);
        acc[1] = __builtin_amdgcn_mfma_f32_16x16x32_bf16(a, *(const bf16x8*)(b1 + k0), acc[1], 0, 0, 0);
        acc[2] = __builtin_amdgcn_mfma_f32_16x16x32_bf16(a, *(const bf16x8*)(b2 + k0), acc[2], 0, 0, 0);
        acc[3] = __builtin_amdgcn_mfma_f32_16x16x32_bf16(a, *(const bf16x8*)(b3 + k0), acc[3], 0, 0, 0);
    }
    float bv0 = bias[nb + 0 + c], bv1 = bias[nb + 16 + c];
    float bv2 = bias[nb + 32 + c], bv3 = bias[nb + 48 + c];
#pragma unroll
    for (int r = 0; r < 4; ++r) {
        int row = mrow + 4 * g + r;
        float l0 = acc[0][r] + bv0;
        float l1 = acc[1][r] + bv1;
        float l2 = acc[2][r] + bv2;
        float l3 = acc[3][r] + bv3;
        float m = fmaxf(fmaxf(l0, l1), fmaxf(l2, l3));
        for (int mk = 1; mk <= 8; mk <<= 1) m = fmaxf(m, __shfl_xor(m, mk));
        float s = expf(l0 - m) + expf(l1 - m) + expf(l2 - m) + expf(l3 - m);
        for (int mk = 1; mk <= 8; mk <<= 1) s += __shfl_xor(s, mk);
        float* orow = out + (size_t)row * VV + nb;
        orow[ 0 + c] = l0;
        orow[16 + c] = l1;
        orow[32 + c] = l2;
        orow[48 + c] = l3;
        if (c == 0) {
            pm[(size_t)row * NT + blockIdx.y] = m;
            ps[(size_t)row * NT + blockIdx.y] = s;
        }
    }
}

// ---------------- per-row logsumexp merge ----------------
__global__ __launch_bounds__(256) void lse_reduce(
    const float* __restrict__ pm, const float* __restrict__ ps,
    float* __restrict__ lse)
{
    int row = blockIdx.x;
    int tid = threadIdx.x, wid = tid >> 6, lane = tid & 63;
    __shared__ float smax[4], ssum[4];
    float m = -1e30f;
    for (int i = tid; i < NT; i += 256) m = fmaxf(m, pm[(size_t)row * NT + i]);
    for (int mk = 32; mk >= 1; mk >>= 1) m = fmaxf(m, __shfl_xor(m, mk));
    if (lane == 0) smax[wid] = m;
    __syncthreads();
    m = fmaxf(fmaxf(smax[0], smax[1]), fmaxf(smax[2], smax[3]));
    float s = 0.f;
    for (int i = tid; i < NT; i += 256)
        s += ps[(size_t)row * NT + i] * expf(pm[(size_t)row * NT + i] - m);
    for (int mk = 32; mk >= 1; mk >>= 1) s += __shfl_xor(s, mk);
    if (lane == 0) ssum[wid] = s;
    __syncthreads();
    if (tid == 0) lse[row] = m + logf(ssum[0] + ssum[1] + ssum[2] + ssum[3]);
}

// ---------------- logp = logits - lse[row], in place ----------------
__global__ __launch_bounds__(256) void sub_lse(float* __restrict__ out,
                                               const float* __restrict__ lse)
{
    int row = blockIdx.y;
    int idx = blockIdx.x * blockDim.x + threadIdx.x;
    if (idx < VV / 4) {
        float L = lse[row];
        float4* p = (float4*)(out + (size_t)row * VV) + idx;
        float4 v = *p;
        v.x -= L; v.y -= L; v.z -= L; v.w -= L;
        *p = v;
    }
}

extern "C" void kernel_launch(void* const* d_in, const int* in_sizes, int n_in,
                              void* d_out, int out_size, void* d_ws, size_t ws_size,
                              hipStream_t stream)
{
    const int*           nodes     = (const int*)d_in[0];
    const unsigned char* edges_raw = (const unsigned char*)d_in[1];
    const float* emb    = (const float*)d_in[2];
    const float* ecWih  = (const float*)d_in[3];
    const float* ecWhh  = (const float*)d_in[4];
    const float* ecbih  = (const float*)d_in[5];
    const float* ecbhh  = (const float*)d_in[6];
    const float* esWih  = (const float*)d_in[7];
    const float* esWhh  = (const float*)d_in[8];
    const float* esbih  = (const float*)d_in[9];
    const float* esbhh  = (const float*)d_in[10];
    const float* dcWih  = (const float*)d_in[11];
    const float* dcWhh  = (const float*)d_in[12];
    const float* dcbih  = (const float*)d_in[13];
    const float* dcbhh  = (const float*)d_in[14];
    const float* dsWih  = (const float*)d_in[15];
    const float* dsWhh  = (const float*)d_in[16];
    const float* dsbih  = (const float*)d_in[17];
    const float* dsbhh  = (const float*)d_in[18];
    const float* W_mean = (const float*)d_in[19];
    const float* b_mean = (const float*)d_in[20];
    const float* W_logv = (const float*)d_in[21];
    const float* b_logv = (const float*)d_in[22];
    const float* W_l2h  = (const float*)d_in[23];
    const float* b_l2h  = (const float*)d_in[24];
    const float* W_out  = (const float*)d_in[25];
    const float* b_out  = (const float*)d_in[26];
    const float* enc_init = (const float*)d_in[27];
    const float* eps    = (const float*)d_in[28];

    float* out      = (float*)d_out;
    float* out_mean = out + (size_t)TT * DD * VV;
    float* out_logv = out_mean + DD * ZZ;
    float* out_z    = out_logv + DD * ZZ;

    char* ws = (char*)d_ws;
    float*          hb0     = (float*)(ws + 0);                 // 128 KB
    float*          hb1     = (float*)(ws + 131072);            // 128 KB
    __hip_bfloat16* outs_bf = (__hip_bfloat16*)(ws + 262144);   // 2 MB
    __hip_bfloat16* Wb      = (__hip_bfloat16*)(ws + 2359296);  // 16.4 MB
    float*          pm      = (float*)(ws + 18743296);          // 8.2 MB
    float*          ps      = (float*)(ws + 26935296);          // 8.2 MB
    float*          lse     = (float*)(ws + 35127296);          // 16 KB
    unsigned char*  ecan    = (unsigned char*)(ws + 35143680);  // 4 KB

    edge_canon_k<<<1, 256, 0, stream>>>(edges_raw, ecan);
    conv_bf16<<<2048, 256, 0, stream>>>(W_out, Wb, VV * HH);

    // encoder
    for (int t = 0; t < TT; ++t) {
        const float* hin = (t == 0) ? enc_init : ((t & 1) ? hb0 : hb1);
        float* hout = (t & 1) ? hb1 : hb0;
        gru_step<<<dim3(8, 32), 128, 0, stream>>>(
            nodes + t * DD, ecan + t * DD, emb,
            ecWih, ecWhh, ecbih, ecbhh, esWih, esWhh, esbih, esbhh,
            hin, hout, (__hip_bfloat16*)nullptr);
    }
    // hid = hb1
    latent_k<<<128, 256, 0, stream>>>(hb1, W_mean, b_mean, W_logv, b_logv, eps,
                                      out_mean, out_logv, out_z);
    h0_k<<<128, 256, 0, stream>>>(out_z, W_l2h, b_l2h, hb0);

    // decoder (h0 in hb0)
    for (int t = 0; t < TT; ++t) {
        const float* hin = (t & 1) ? hb1 : hb0;
        float* hout = (t & 1) ? hb0 : hb1;
        gru_step<<<dim3(8, 32), 128, 0, stream>>>(
            nodes + t * DD, ecan + t * DD, emb,
            dcWih, dcWhh, dcbih, dcbhh, dsWih, dsWhh, dsbih, dsbhh,
            hin, hout, outs_bf + (size_t)t * DD * HH);
    }

    out_gemm<<<dim3(64, NT), 256, 0, stream>>>(outs_bf, Wb, b_out, out, pm, ps);
    lse_reduce<<<4096, 256, 0, stream>>>(pm, ps, lse);
    sub_lse<<<dim3(32, 4096), 256, 0, stream>>>(out, lse);
}

// Round 2
// 1956.240 us; speedup vs baseline: 1.8708x; 1.8708x over previous
//
#include <hip/hip_runtime.h>
#include <hip/hip_bf16.h>

#define TT 32
#define DD 128
#define HH 256
#define VV 32000
#define ZZ 256
#define MM 4096          // TT*DD rows
#define NT 250           // VV/128 n-tiles for pm/ps

typedef __attribute__((ext_vector_type(8))) short bf16x8;
typedef __attribute__((ext_vector_type(4))) float f32x4;

static __device__ inline unsigned short f2bf(float x) {
    __hip_bfloat16 h = __float2bfloat16(x);
    return *(unsigned short*)&h;
}

// ---------------- edges canonicalizer (bool-vs-int32 layout detect) ----------------
__global__ void edge_canon_k(const unsigned char* __restrict__ eb,
                             unsigned char* __restrict__ canon)
{
    __shared__ int flag;
    if (threadIdx.x == 0) flag = 0;
    __syncthreads();
    int acc = 0;
    for (int i = threadIdx.x; i < TT * DD; i += 256)
        if (i & 3) acc |= eb[i];
    if (acc) atomicOr(&flag, 1);
    __syncthreads();
    const bool is_i32 = (flag == 0);
    for (int i = threadIdx.x; i < TT * DD; i += 256)
        canon[i] = is_i32 ? eb[4 * (size_t)i] : eb[i];
}

// ---------------- f32 -> bf16 conversion ----------------
__global__ void conv_bf16(const float* __restrict__ src,
                          __hip_bfloat16* __restrict__ dst, int n)
{
    int stride = gridDim.x * blockDim.x;
    for (int i = blockIdx.x * blockDim.x + threadIdx.x; i * 4 < n; i += stride) {
        float4 v = ((const float4*)src)[i];
        ushort4 u;
        u.x = f2bf(v.x); u.y = f2bf(v.y); u.z = f2bf(v.z); u.w = f2bf(v.w);
        *(ushort4*)(dst + 4 * (size_t)i) = u;
    }
}

// ---------------- gather token rows of emb -> bf16 A [4096][256] ----------------
__global__ __launch_bounds__(256) void gather_a(
    const int* __restrict__ nodes, const float* __restrict__ emb,
    __hip_bfloat16* __restrict__ Abf)
{
    const int row = blockIdx.x * 4 + (threadIdx.x >> 6);
    const int cl  = threadIdx.x & 63;
    const int tok = nodes[row];
    float4 v = ((const float4*)(emb + (size_t)tok * HH))[cl];
    ushort4 u;
    u.x = f2bf(v.x); u.y = f2bf(v.y); u.z = f2bf(v.z); u.w = f2bf(v.w);
    *(ushort4*)(Abf + (size_t)row * HH + cl * 4) = u;
}

// ---------------- unified tiled GEMM: C[4096][ldc] = A[4096][256] x B[ldc][256]^T ----------------
// BM=64, BN=128, K=256 fully staged in LDS (96KB), XOR-swizzled.
template<bool WRITE_C, bool HAS_BIAS, bool LSE_PARTIAL, bool LSE_SUB>
__global__ __launch_bounds__(256) void gemm256(
    const __hip_bfloat16* __restrict__ A,
    const __hip_bfloat16* __restrict__ B,
    int ldc,
    const float* __restrict__ bias,
    const float* __restrict__ lse,
    float* __restrict__ C,
    float* __restrict__ pm, float* __restrict__ ps, int ntiles)
{
    __shared__ __align__(16) char lds[96 * 1024];
    char* ldsA = lds;              // 32KB: 64 rows x 512B
    char* ldsB = lds + 32768;      // 64KB: 128 rows x 512B

    const int tid = threadIdx.x;
    const int m0 = blockIdx.x * 64;
    const int n0 = blockIdx.y * 128;

    // stage A (2048 x 16B chunks)
#pragma unroll
    for (int i = 0; i < 8; ++i) {
        int ci = i * 256 + tid;
        int row = ci >> 5, k16 = ci & 31;
        bf16x8 v = *(const bf16x8*)(A + (size_t)(m0 + row) * HH + k16 * 8);
        *(bf16x8*)(ldsA + row * 512 + ((k16 ^ (row & 7)) * 16)) = v;
    }
    // stage B (4096 x 16B chunks)
#pragma unroll
    for (int i = 0; i < 16; ++i) {
        int ci = i * 256 + tid;
        int row = ci >> 5, k16 = ci & 31;
        bf16x8 v = *(const bf16x8*)(B + (size_t)(n0 + row) * HH + k16 * 8);
        *(bf16x8*)(ldsB + row * 512 + ((k16 ^ (row & 7)) * 16)) = v;
    }
    __syncthreads();

    const int w = tid >> 6, lane = tid & 63;
    const int g = lane >> 4, c = lane & 15;

    f32x4 acc[4][2];
#pragma unroll
    for (int mf = 0; mf < 4; ++mf)
#pragma unroll
        for (int nf = 0; nf < 2; ++nf) acc[mf][nf] = (f32x4){0, 0, 0, 0};

#pragma unroll
    for (int ks = 0; ks < 8; ++ks) {
        bf16x8 af[4], bfr[2];
#pragma unroll
        for (int mf = 0; mf < 4; ++mf) {
            int row = mf * 16 + c;
            af[mf] = *(const bf16x8*)(ldsA + row * 512 + (((ks * 4 + g) ^ (row & 7)) * 16));
        }
#pragma unroll
        for (int nf = 0; nf < 2; ++nf) {
            int row = w * 32 + nf * 16 + c;
            bfr[nf] = *(const bf16x8*)(ldsB + row * 512 + (((ks * 4 + g) ^ (row & 7)) * 16));
        }
#pragma unroll
        for (int mf = 0; mf < 4; ++mf)
#pragma unroll
            for (int nf = 0; nf < 2; ++nf)
                acc[mf][nf] = __builtin_amdgcn_mfma_f32_16x16x32_bf16(
                    af[mf], bfr[nf], acc[mf][nf], 0, 0, 0);
    }

    float bv[2] = {0.f, 0.f};
    if (HAS_BIAS) {
#pragma unroll
        for (int nf = 0; nf < 2; ++nf) bv[nf] = bias[n0 + w * 32 + nf * 16 + c];
    }

    __syncthreads();  // all frag reads done; LDS reusable

    if (LSE_PARTIAL) {
        float* red = (float*)lds;   // [4][64][2]
#pragma unroll
        for (int mf = 0; mf < 4; ++mf) {
#pragma unroll
            for (int r = 0; r < 4; ++r) {
                float l0 = acc[mf][0][r] + bv[0];
                float l1 = acc[mf][1][r] + bv[1];
                float m = fmaxf(l0, l1);
                for (int mk = 1; mk <= 8; mk <<= 1) m = fmaxf(m, __shfl_xor(m, mk));
                float s = expf(l0 - m) + expf(l1 - m);
                for (int mk = 1; mk <= 8; mk <<= 1) s += __shfl_xor(s, mk);
                if (c == 0) {
                    int row = mf * 16 + 4 * g + r;
                    red[(w * 64 + row) * 2 + 0] = m;
                    red[(w * 64 + row) * 2 + 1] = s;
                }
            }
        }
        __syncthreads();
        if (tid < 64) {
            float* red2 = (float*)lds;
            float m = red2[tid * 2], s;
            for (int ww = 1; ww < 4; ++ww) m = fmaxf(m, red2[(ww * 64 + tid) * 2]);
            s = 0.f;
            for (int ww = 0; ww < 4; ++ww)
                s += red2[(ww * 64 + tid) * 2 + 1] * expf(red2[(ww * 64 + tid) * 2] - m);
            pm[(size_t)(m0 + tid) * ntiles + blockIdx.y] = m;
            ps[(size_t)(m0 + tid) * ntiles + blockIdx.y] = s;
        }
    }

    if (WRITE_C) {
        float* ldso = (float*)lds;  // [64][128]
#pragma unroll
        for (int mf = 0; mf < 4; ++mf)
#pragma unroll
            for (int nf = 0; nf < 2; ++nf)
#pragma unroll
                for (int r = 0; r < 4; ++r)
                    ldso[(mf * 16 + 4 * g + r) * 128 + w * 32 + nf * 16 + c] =
                        acc[mf][nf][r] + bv[nf];
        __syncthreads();
#pragma unroll
        for (int i = 0; i < 8; ++i) {
            int fi = i * 256 + tid;           // 2048 float4s
            int row = fi >> 5, c4 = fi & 31;
            float4 v = ((const float4*)ldso)[fi];
            if (LSE_SUB) {
                float L = lse[m0 + row];
                v.x -= L; v.y -= L; v.z -= L; v.w -= L;
            }
            *(float4*)(C + (size_t)(m0 + row) * ldc + n0 + c4 * 4) = v;
        }
    }
}

// ---------------- GRU recurrent step: gh = h@Whh_sel^T, gates, h_new ----------------
// grid (8, 32), block 128 = 32 j x 4 d
__global__ __launch_bounds__(128) void gru_step2(
    const unsigned char* __restrict__ edges_t,
    const float* __restrict__ gi_t,     // [128][3072] for this t
    int phase_off,                       // 0 enc, 1536 dec
    const float* __restrict__ Whh_c, const float* __restrict__ bih_c,
    const float* __restrict__ bhh_c,
    const float* __restrict__ Whh_s, const float* __restrict__ bih_s,
    const float* __restrict__ bhh_s,
    const float* __restrict__ h_in, float* __restrict__ h_out,
    __hip_bfloat16* __restrict__ outs_t)
{
    const int jl = threadIdx.x & 31;
    const int dl = threadIdx.x >> 5;
    const int j  = blockIdx.x * 32 + jl;
    const int d  = blockIdx.y * 4 + dl;

    const bool e = edges_t[d] != 0;
    const float* __restrict__ Whh = e ? Whh_c : Whh_s;
    const float* __restrict__ bih = e ? bih_c : bih_s;
    const float* __restrict__ bhh = e ? bhh_c : bhh_s;
    const float* __restrict__ gi  = gi_t + (size_t)d * 3072 + phase_off + (e ? 0 : 768);

    const float4* __restrict__ h4 = (const float4*)(h_in + (size_t)d * HH);
    const float4* __restrict__ wr = (const float4*)(Whh + (size_t)j * HH);
    const float4* __restrict__ wz = (const float4*)(Whh + (size_t)(j + HH) * HH);
    const float4* __restrict__ wn = (const float4*)(Whh + (size_t)(j + 2 * HH) * HH);

    float sr = 0.f, sz = 0.f, sn = 0.f;
#pragma unroll 8
    for (int k = 0; k < HH / 4; ++k) {
        float4 hv = h4[k];
        float4 a = wr[k], b = wz[k], cc = wn[k];
        sr += hv.x * a.x + hv.y * a.y + hv.z * a.z + hv.w * a.w;
        sz += hv.x * b.x + hv.y * b.y + hv.z * b.z + hv.w * b.w;
        sn += hv.x * cc.x + hv.y * cc.y + hv.z * cc.z + hv.w * cc.w;
    }
    float ir = gi[j]          + bih[j];
    float iz = gi[j + HH]     + bih[j + HH];
    float in_ = gi[j + 2*HH]  + bih[j + 2 * HH];
    float hr = sr + bhh[j];
    float hz = sz + bhh[j + HH];
    float hn = sn + bhh[j + 2 * HH];
    float r  = 1.f / (1.f + expf(-(ir + hr)));
    float zg = 1.f / (1.f + expf(-(iz + hz)));
    float n  = tanhf(in_ + r * hn);
    float hprev = h_in[(size_t)d * HH + j];
    float hnew = (1.f - zg) * n + zg * hprev;
    h_out[(size_t)d * HH + j] = hnew;
    if (outs_t) outs_t[(size_t)d * HH + j] = __float2bfloat16(hnew);
}

// ---------------- latent head ----------------
__global__ __launch_bounds__(256) void latent_k(
    const float* __restrict__ hid, const float* __restrict__ W_mean,
    const float* __restrict__ b_mean, const float* __restrict__ W_logv,
    const float* __restrict__ b_logv, const float* __restrict__ eps,
    float* __restrict__ out_mean, float* __restrict__ out_logv,
    float* __restrict__ out_z)
{
    int idx = blockIdx.x * blockDim.x + threadIdx.x;  // D*Z = 32768
    int d = idx >> 8, zi = idx & 255;
    const float4* hv = (const float4*)(hid + (size_t)d * HH);
    const float4* wm = (const float4*)(W_mean + (size_t)zi * HH);
    const float4* wl = (const float4*)(W_logv + (size_t)zi * HH);
    float sm = 0.f, sl = 0.f;
#pragma unroll 8
    for (int k = 0; k < HH / 4; ++k) {
        float4 h4 = hv[k], m4 = wm[k], l4 = wl[k];
        sm += h4.x * m4.x + h4.y * m4.y + h4.z * m4.z + h4.w * m4.w;
        sl += h4.x * l4.x + h4.y * l4.y + h4.z * l4.z + h4.w * l4.w;
    }
    float mean = sm + b_mean[zi];
    float logv = sl + b_logv[zi];
    float zval = eps[idx] * expf(0.5f * logv) + mean;
    out_mean[idx] = mean;
    out_logv[idx] = logv;
    out_z[idx]    = zval;
}

// ---------------- h0 = z @ W_l2h.T + b ----------------
__global__ __launch_bounds__(256) void h0_k(
    const float* __restrict__ z, const float* __restrict__ W_l2h,
    const float* __restrict__ b_l2h, float* __restrict__ h0)
{
    int idx = blockIdx.x * blockDim.x + threadIdx.x;  // D*H = 32768
    int d = idx >> 8, j = idx & 255;
    const float4* zv = (const float4*)(z + (size_t)d * ZZ);
    const float4* wv = (const float4*)(W_l2h + (size_t)j * ZZ);
    float s = 0.f;
#pragma unroll 8
    for (int k = 0; k < ZZ / 4; ++k) {
        float4 a = zv[k], b = wv[k];
        s += a.x * b.x + a.y * b.y + a.z * b.z + a.w * b.w;
    }
    h0[idx] = s + b_l2h[j];
}

// ---------------- per-row logsumexp merge ----------------
__global__ __launch_bounds__(256) void lse_reduce(
    const float* __restrict__ pm, const float* __restrict__ ps,
    float* __restrict__ lse)
{
    int row = blockIdx.x;
    int tid = threadIdx.x, wid = tid >> 6, lane = tid & 63;
    __shared__ float smax[4], ssum[4];
    float m = -1e30f;
    for (int i = tid; i < NT; i += 256) m = fmaxf(m, pm[(size_t)row * NT + i]);
    for (int mk = 32; mk >= 1; mk >>= 1) m = fmaxf(m, __shfl_xor(m, mk));
    if (lane == 0) smax[wid] = m;
    __syncthreads();
    m = fmaxf(fmaxf(smax[0], smax[1]), fmaxf(smax[2], smax[3]));
    float s = 0.f;
    for (int i = tid; i < NT; i += 256)
        s += ps[(size_t)row * NT + i] * expf(pm[(size_t)row * NT + i] - m);
    for (int mk = 32; mk >= 1; mk >>= 1) s += __shfl_xor(s, mk);
    if (lane == 0) ssum[wid] = s;
    __syncthreads();
    if (tid == 0) lse[row] = m + logf(ssum[0] + ssum[1] + ssum[2] + ssum[3]);
}

extern "C" void kernel_launch(void* const* d_in, const int* in_sizes, int n_in,
                              void* d_out, int out_size, void* d_ws, size_t ws_size,
                              hipStream_t stream)
{
    const int*           nodes     = (const int*)d_in[0];
    const unsigned char* edges_raw = (const unsigned char*)d_in[1];
    const float* emb    = (const float*)d_in[2];
    const float* ecWih  = (const float*)d_in[3];
    const float* ecWhh  = (const float*)d_in[4];
    const float* ecbih  = (const float*)d_in[5];
    const float* ecbhh  = (const float*)d_in[6];
    const float* esWih  = (const float*)d_in[7];
    const float* esWhh  = (const float*)d_in[8];
    const float* esbih  = (const float*)d_in[9];
    const float* esbhh  = (const float*)d_in[10];
    const float* dcWih  = (const float*)d_in[11];
    const float* dcWhh  = (const float*)d_in[12];
    const float* dcbih  = (const float*)d_in[13];
    const float* dcbhh  = (const float*)d_in[14];
    const float* dsWih  = (const float*)d_in[15];
    const float* dsWhh  = (const float*)d_in[16];
    const float* dsbih  = (const float*)d_in[17];
    const float* dsbhh  = (const float*)d_in[18];
    const float* W_mean = (const float*)d_in[19];
    const float* b_mean = (const float*)d_in[20];
    const float* W_logv = (const float*)d_in[21];
    const float* b_logv = (const float*)d_in[22];
    const float* W_l2h  = (const float*)d_in[23];
    const float* b_l2h  = (const float*)d_in[24];
    const float* W_out  = (const float*)d_in[25];
    const float* b_out  = (const float*)d_in[26];
    const float* enc_init = (const float*)d_in[27];
    const float* eps    = (const float*)d_in[28];

    float* out      = (float*)d_out;
    float* out_mean = out + (size_t)TT * DD * VV;
    float* out_logv = out_mean + DD * ZZ;
    float* out_z    = out_logv + DD * ZZ;
    float* gi       = out;                  // scratch in logits region: [4096][3072]

    char* ws = (char*)d_ws;
    float*          hb0     = (float*)(ws + 0);
    float*          hb1     = (float*)(ws + 131072);
    __hip_bfloat16* outs_bf = (__hip_bfloat16*)(ws + 262144);    // 2MB
    __hip_bfloat16* A_bf    = (__hip_bfloat16*)(ws + 2359296);   // 2MB
    __hip_bfloat16* Wb      = (__hip_bfloat16*)(ws + 4456448);   // 16MB
    __hip_bfloat16* B_all   = (__hip_bfloat16*)(ws + 20840448);  // 1.5MB [3072][256]
    float*          pm      = (float*)(ws + 22413312);           // 4MB
    float*          ps      = (float*)(ws + 26509312);           // 4MB
    float*          lse     = (float*)(ws + 30605312);           // 16KB
    unsigned char*  ecan    = (unsigned char*)(ws + 30621696);   // 4KB

    edge_canon_k<<<1, 256, 0, stream>>>(edges_raw, ecan);
    conv_bf16<<<2048, 256, 0, stream>>>(W_out, Wb, VV * HH);
    conv_bf16<<<192, 256, 0, stream>>>(ecWih, B_all + 0 * 768 * HH, 768 * HH);
    conv_bf16<<<192, 256, 0, stream>>>(esWih, B_all + 1 * 768 * HH, 768 * HH);
    conv_bf16<<<192, 256, 0, stream>>>(dcWih, B_all + 2 * 768 * HH, 768 * HH);
    conv_bf16<<<192, 256, 0, stream>>>(dsWih, B_all + 3 * 768 * HH, 768 * HH);
    gather_a<<<1024, 256, 0, stream>>>(nodes, emb, A_bf);

    // gi[4096][3072] = A_bf x B_all^T  (into d_out scratch)
    gemm256<true, false, false, false><<<dim3(64, 24), 256, 0, stream>>>(
        A_bf, B_all, 3072, nullptr, nullptr, gi, nullptr, nullptr, 0);

    // encoder
    for (int t = 0; t < TT; ++t) {
        const float* hin = (t == 0) ? enc_init : ((t & 1) ? hb0 : hb1);
        float* hout = (t & 1) ? hb1 : hb0;
        gru_step2<<<dim3(8, 32), 128, 0, stream>>>(
            ecan + t * DD, gi + (size_t)t * DD * 3072, 0,
            ecWhh, ecbih, ecbhh, esWhh, esbih, esbhh,
            hin, hout, (__hip_bfloat16*)nullptr);
    }
    latent_k<<<128, 256, 0, stream>>>(hb1, W_mean, b_mean, W_logv, b_logv, eps,
                                      out_mean, out_logv, out_z);
    h0_k<<<128, 256, 0, stream>>>(out_z, W_l2h, b_l2h, hb0);

    // decoder
    for (int t = 0; t < TT; ++t) {
        const float* hin = (t & 1) ? hb1 : hb0;
        float* hout = (t & 1) ? hb0 : hb1;
        gru_step2<<<dim3(8, 32), 128, 0, stream>>>(
            ecan + t * DD, gi + (size_t)t * DD * 3072, 1536,
            dcWhh, dcbih, dcbhh, dsWhh, dsbih, dsbhh,
            hin, hout, outs_bf + (size_t)t * DD * HH);
    }

    // pass A: LSE partials only
    gemm256<false, true, true, false><<<dim3(64, NT), 256, 0, stream>>>(
        outs_bf, Wb, VV, b_out, nullptr, nullptr, pm, ps, NT);
    lse_reduce<<<4096, 256, 0, stream>>>(pm, ps, lse);
    // pass B: recompute, write logp
    gemm256<true, true, false, true><<<dim3(64, NT), 256, 0, stream>>>(
        outs_bf, Wb, VV, b_out, lse, out, nullptr, nullptr, NT);
}

// Round 3
// 1652.533 us; speedup vs baseline: 2.2146x; 1.1838x over previous
//
#include <hip/hip_runtime.h>
#include <hip/hip_bf16.h>

#define TT 32
#define DD 128
#define HH 256
#define VV 32000
#define ZZ 256
#define NTL 50            // n-slabs for V-GEMM (50 x 640 = 32000)

typedef __attribute__((ext_vector_type(8))) short bf16x8;
typedef __attribute__((ext_vector_type(4))) float f32x4;

static __device__ inline unsigned short f2bf(float x) {
    __hip_bfloat16 h = __float2bfloat16(x);
    return *(unsigned short*)&h;
}

// ---------------- edges canonicalizer (bool-vs-int32 layout detect) ----------------
__global__ void edge_canon_k(const unsigned char* __restrict__ eb,
                             unsigned char* __restrict__ canon)
{
    __shared__ int flag;
    if (threadIdx.x == 0) flag = 0;
    __syncthreads();
    int acc = 0;
    for (int i = threadIdx.x; i < TT * DD; i += 256)
        if (i & 3) acc |= eb[i];
    if (acc) atomicOr(&flag, 1);
    __syncthreads();
    const bool is_i32 = (flag == 0);
    for (int i = threadIdx.x; i < TT * DD; i += 256)
        canon[i] = is_i32 ? eb[4 * (size_t)i] : eb[i];
}

// ---------------- f32 -> bf16 conversion ----------------
__global__ void conv_bf16(const float* __restrict__ src,
                          __hip_bfloat16* __restrict__ dst, int n)
{
    int stride = gridDim.x * blockDim.x;
    for (int i = blockIdx.x * blockDim.x + threadIdx.x; i * 4 < n; i += stride) {
        float4 v = ((const float4*)src)[i];
        ushort4 u;
        u.x = f2bf(v.x); u.y = f2bf(v.y); u.z = f2bf(v.z); u.w = f2bf(v.w);
        *(ushort4*)(dst + 4 * (size_t)i) = u;
    }
}

// ---------------- gather token rows of emb -> bf16 A [4096][256] ----------------
__global__ __launch_bounds__(256) void gather_a(
    const int* __restrict__ nodes, const float* __restrict__ emb,
    __hip_bfloat16* __restrict__ Abf)
{
    const int row = blockIdx.x * 4 + (threadIdx.x >> 6);
    const int cl  = threadIdx.x & 63;
    const int tok = nodes[row];
    float4 v = ((const float4*)(emb + (size_t)tok * HH))[cl];
    ushort4 u;
    u.x = f2bf(v.x); u.y = f2bf(v.y); u.z = f2bf(v.z); u.w = f2bf(v.w);
    *(ushort4*)(Abf + (size_t)row * HH + cl * 4) = u;
}

// ============ register-stationary GEMM: C[4096][ldc] = A[4096][256] @ B[ldc][256]^T ============
// No LDS staging, no barriers. Block = 4 waves; wave owns 16 m-rows, A held in
// 8 bf16x8 regs for the whole block. Grid (64 m-blocks, ntiles slabs), m-fastest
// so concurrent blocks share the B slab through L2. Each slab = nchunks * 64 cols.
template<bool WRITE_C, bool HAS_BIAS, bool LSE_PARTIAL, bool LSE_SUB>
__global__ __launch_bounds__(256, 4) void gemm_rs(
    const __hip_bfloat16* __restrict__ A,
    const __hip_bfloat16* __restrict__ B,
    int ldc, int nchunks, int ntiles,
    const float* __restrict__ bias,
    const float* __restrict__ lse,
    float* __restrict__ C,
    float* __restrict__ pm, float* __restrict__ ps)
{
    __shared__ float lds_st[WRITE_C ? (4 * 16 * 68) : 1];

    const int tid  = threadIdx.x;
    const int w    = tid >> 6;
    const int lane = tid & 63;
    const int g    = lane >> 4;
    const int c    = lane & 15;
    const int m0   = blockIdx.x * 64;
    const int row16 = m0 + w * 16;
    const int n0   = blockIdx.y * (nchunks * 64);

    // A fragments for full K=256, loaded once (L2-hot; 8 x 16B per lane)
    bf16x8 a[8];
    {
        const __hip_bfloat16* arow = A + (size_t)(row16 + c) * HH + g * 8;
#pragma unroll
        for (int ks = 0; ks < 8; ++ks) a[ks] = *(const bf16x8*)(arow + ks * 32);
    }

    float mrun[4], srun[4];
#pragma unroll
    for (int r = 0; r < 4; ++r) { mrun[r] = -3.0e38f; srun[r] = 0.f; }

    float lsev[4];
    if (LSE_SUB) {
#pragma unroll
        for (int r = 0; r < 4; ++r) lsev[r] = lse[row16 + 4 * g + r];
    }

    for (int nc = 0; nc < nchunks; ++nc) {
        const int nb = n0 + nc * 64;
        const __hip_bfloat16* b0p = B + (size_t)(nb +  0 + c) * HH + g * 8;
        const __hip_bfloat16* b1p = B + (size_t)(nb + 16 + c) * HH + g * 8;
        const __hip_bfloat16* b2p = B + (size_t)(nb + 32 + c) * HH + g * 8;
        const __hip_bfloat16* b3p = B + (size_t)(nb + 48 + c) * HH + g * 8;

        f32x4 acc[4];
#pragma unroll
        for (int nf = 0; nf < 4; ++nf) acc[nf] = (f32x4){0.f, 0.f, 0.f, 0.f};

#pragma unroll
        for (int ks = 0; ks < 8; ++ks) {
            bf16x8 b0 = *(const bf16x8*)(b0p + ks * 32);
            bf16x8 b1 = *(const bf16x8*)(b1p + ks * 32);
            bf16x8 b2 = *(const bf16x8*)(b2p + ks * 32);
            bf16x8 b3 = *(const bf16x8*)(b3p + ks * 32);
            acc[0] = __builtin_amdgcn_mfma_f32_16x16x32_bf16(a[ks], b0, acc[0], 0, 0, 0);
            acc[1] = __builtin_amdgcn_mfma_f32_16x16x32_bf16(a[ks], b1, acc[1], 0, 0, 0);
            acc[2] = __builtin_amdgcn_mfma_f32_16x16x32_bf16(a[ks], b2, acc[2], 0, 0, 0);
            acc[3] = __builtin_amdgcn_mfma_f32_16x16x32_bf16(a[ks], b3, acc[3], 0, 0, 0);
        }

        float bv[4] = {0.f, 0.f, 0.f, 0.f};
        if (HAS_BIAS) {
#pragma unroll
            for (int nf = 0; nf < 4; ++nf) bv[nf] = bias[nb + nf * 16 + c];
        }

        if (LSE_PARTIAL) {
            // per-lane online max/sum over this lane's 4 columns, 4 rows
#pragma unroll
            for (int r = 0; r < 4; ++r) {
                float l0 = acc[0][r] + bv[0];
                float l1 = acc[1][r] + bv[1];
                float l2 = acc[2][r] + bv[2];
                float l3 = acc[3][r] + bv[3];
                float mc = fmaxf(fmaxf(l0, l1), fmaxf(l2, l3));
                float mn = fmaxf(mrun[r], mc);
                srun[r] = srun[r] * expf(mrun[r] - mn)
                        + expf(l0 - mn) + expf(l1 - mn)
                        + expf(l2 - mn) + expf(l3 - mn);
                mrun[r] = mn;
            }
        }

        if (WRITE_C) {
            const int base = w * (16 * 68);
#pragma unroll
            for (int nf = 0; nf < 4; ++nf)
#pragma unroll
                for (int r = 0; r < 4; ++r) {
                    float v = acc[nf][r] + bv[nf];
                    if (LSE_SUB) v -= lsev[r];
                    lds_st[base + (4 * g + r) * 68 + nf * 16 + c] = v;
                }
            // wave-local transpose read-back -> coalesced 256B-per-row stores
#pragma unroll
            for (int i = 0; i < 4; ++i) {
                int lr = i * 4 + g;
                float4 v = *(const float4*)&lds_st[base + lr * 68 + c * 4];
                *(float4*)(C + (size_t)(row16 + lr) * ldc + nb + c * 4) = v;
            }
        }
    }

    if (LSE_PARTIAL) {
        // merge (m,s) across the 16 c-lanes, then write one partial per slab
#pragma unroll
        for (int r = 0; r < 4; ++r) {
            float m = mrun[r], s = srun[r];
#pragma unroll
            for (int mk = 1; mk <= 8; mk <<= 1) {
                float m2 = __shfl_xor(m, mk);
                float s2 = __shfl_xor(s, mk);
                float mn = fmaxf(m, m2);
                s = s * expf(m - mn) + s2 * expf(m2 - mn);
                m = mn;
            }
            if (c == 0) {
                int row = row16 + 4 * g + r;
                pm[(size_t)row * ntiles + blockIdx.y] = m;
                ps[(size_t)row * ntiles + blockIdx.y] = s;
            }
        }
    }
}

// ---------------- GRU recurrent step v3: 8-way k-split, shfl reduce ----------------
// grid (8 j-blocks, 128 d), block 256 = (j:32, kq:8). Edge select is block-uniform.
__global__ __launch_bounds__(256) void gru_step3(
    const unsigned char* __restrict__ edges_t,
    const float* __restrict__ gi_t, int phase_off,
    const float* __restrict__ Whh_c, const float* __restrict__ bih_c,
    const float* __restrict__ bhh_c,
    const float* __restrict__ Whh_s, const float* __restrict__ bih_s,
    const float* __restrict__ bhh_s,
    const float* __restrict__ h_in, float* __restrict__ h_out,
    __hip_bfloat16* __restrict__ outs_t)
{
    const int d  = blockIdx.y;
    const int kq = threadIdx.x & 7;
    const int j  = blockIdx.x * 32 + (threadIdx.x >> 3);
    const bool e = edges_t[d] != 0;

    const float* __restrict__ Whh = e ? Whh_c : Whh_s;
    const float4* __restrict__ h4 = (const float4*)(h_in + (size_t)d * HH);
    const float4* __restrict__ wr = (const float4*)(Whh + (size_t)j * HH);
    const float4* __restrict__ wz = (const float4*)(Whh + (size_t)(j + HH) * HH);
    const float4* __restrict__ wn = (const float4*)(Whh + (size_t)(j + 2 * HH) * HH);

    float sr = 0.f, sz = 0.f, sn = 0.f;
#pragma unroll
    for (int i = 0; i < 8; ++i) {
        int f = i * 8 + kq;                 // lanes (j,kq): 128B-contiguous per j
        float4 hv = h4[f];
        float4 va = wr[f], vb = wz[f], vc = wn[f];
        sr += hv.x * va.x + hv.y * va.y + hv.z * va.z + hv.w * va.w;
        sz += hv.x * vb.x + hv.y * vb.y + hv.z * vb.z + hv.w * vb.w;
        sn += hv.x * vc.x + hv.y * vc.y + hv.z * vc.z + hv.w * vc.w;
    }
    sr += __shfl_xor(sr, 1); sr += __shfl_xor(sr, 2); sr += __shfl_xor(sr, 4);
    sz += __shfl_xor(sz, 1); sz += __shfl_xor(sz, 2); sz += __shfl_xor(sz, 4);
    sn += __shfl_xor(sn, 1); sn += __shfl_xor(sn, 2); sn += __shfl_xor(sn, 4);

    if (kq == 0) {
        const float* __restrict__ bih = e ? bih_c : bih_s;
        const float* __restrict__ bhh = e ? bhh_c : bhh_s;
        const float* __restrict__ gi  = gi_t + (size_t)d * 3072 + phase_off + (e ? 0 : 768);
        float ir  = gi[j]          + bih[j];
        float iz  = gi[j + HH]     + bih[j + HH];
        float in_ = gi[j + 2 * HH] + bih[j + 2 * HH];
        float hr = sr + bhh[j];
        float hz = sz + bhh[j + HH];
        float hn = sn + bhh[j + 2 * HH];
        float rg = 1.f / (1.f + expf(-(ir + hr)));
        float zg = 1.f / (1.f + expf(-(iz + hz)));
        float nn = tanhf(in_ + rg * hn);
        float hprev = h_in[(size_t)d * HH + j];
        float hnew = (1.f - zg) * nn + zg * hprev;
        h_out[(size_t)d * HH + j] = hnew;
        if (outs_t) outs_t[(size_t)d * HH + j] = __float2bfloat16(hnew);
    }
}

// ---------------- latent head ----------------
__global__ __launch_bounds__(256) void latent_k(
    const float* __restrict__ hid, const float* __restrict__ W_mean,
    const float* __restrict__ b_mean, const float* __restrict__ W_logv,
    const float* __restrict__ b_logv, const float* __restrict__ eps,
    float* __restrict__ out_mean, float* __restrict__ out_logv,
    float* __restrict__ out_z)
{
    int idx = blockIdx.x * blockDim.x + threadIdx.x;  // D*Z = 32768
    int d = idx >> 8, zi = idx & 255;
    const float4* hv = (const float4*)(hid + (size_t)d * HH);
    const float4* wm = (const float4*)(W_mean + (size_t)zi * HH);
    const float4* wl = (const float4*)(W_logv + (size_t)zi * HH);
    float sm = 0.f, sl = 0.f;
#pragma unroll 8
    for (int k = 0; k < HH / 4; ++k) {
        float4 h4 = hv[k], m4 = wm[k], l4 = wl[k];
        sm += h4.x * m4.x + h4.y * m4.y + h4.z * m4.z + h4.w * m4.w;
        sl += h4.x * l4.x + h4.y * l4.y + h4.z * l4.z + h4.w * l4.w;
    }
    float mean = sm + b_mean[zi];
    float logv = sl + b_logv[zi];
    float zval = eps[idx] * expf(0.5f * logv) + mean;
    out_mean[idx] = mean;
    out_logv[idx] = logv;
    out_z[idx]    = zval;
}

// ---------------- h0 = z @ W_l2h.T + b ----------------
__global__ __launch_bounds__(256) void h0_k(
    const float* __restrict__ z, const float* __restrict__ W_l2h,
    const float* __restrict__ b_l2h, float* __restrict__ h0)
{
    int idx = blockIdx.x * blockDim.x + threadIdx.x;  // D*H = 32768
    int d = idx >> 8, j = idx & 255;
    const float4* zv = (const float4*)(z + (size_t)d * ZZ);
    const float4* wv = (const float4*)(W_l2h + (size_t)j * ZZ);
    float s = 0.f;
#pragma unroll 8
    for (int k = 0; k < ZZ / 4; ++k) {
        float4 a = zv[k], b = wv[k];
        s += a.x * b.x + a.y * b.y + a.z * b.z + a.w * b.w;
    }
    h0[idx] = s + b_l2h[j];
}

// ---------------- per-row logsumexp merge (one wave per row, nt <= 64) ----------------
__global__ __launch_bounds__(64) void lse_reduce(
    const float* __restrict__ pm, const float* __restrict__ ps,
    float* __restrict__ lse, int nt)
{
    int row = blockIdx.x;
    int l = threadIdx.x;
    float m = (l < nt) ? pm[(size_t)row * nt + l] : -3.0e38f;
    float s = (l < nt) ? ps[(size_t)row * nt + l] : 0.f;
    for (int mk = 1; mk <= 32; mk <<= 1) {
        float m2 = __shfl_xor(m, mk);
        float s2 = __shfl_xor(s, mk);
        float mn = fmaxf(m, m2);
        s = s * expf(m - mn) + s2 * expf(m2 - mn);
        m = mn;
    }
    if (l == 0) lse[row] = m + logf(s);
}

extern "C" void kernel_launch(void* const* d_in, const int* in_sizes, int n_in,
                              void* d_out, int out_size, void* d_ws, size_t ws_size,
                              hipStream_t stream)
{
    const int*           nodes     = (const int*)d_in[0];
    const unsigned char* edges_raw = (const unsigned char*)d_in[1];
    const float* emb    = (const float*)d_in[2];
    const float* ecWih  = (const float*)d_in[3];
    const float* ecWhh  = (const float*)d_in[4];
    const float* ecbih  = (const float*)d_in[5];
    const float* ecbhh  = (const float*)d_in[6];
    const float* esWih  = (const float*)d_in[7];
    const float* esWhh  = (const float*)d_in[8];
    const float* esbih  = (const float*)d_in[9];
    const float* esbhh  = (const float*)d_in[10];
    const float* dcWih  = (const float*)d_in[11];
    const float* dcWhh  = (const float*)d_in[12];
    const float* dcbih  = (const float*)d_in[13];
    const float* dcbhh  = (const float*)d_in[14];
    const float* dsWih  = (const float*)d_in[15];
    const float* dsWhh  = (const float*)d_in[16];
    const float* dsbih  = (const float*)d_in[17];
    const float* dsbhh  = (const float*)d_in[18];
    const float* W_mean = (const float*)d_in[19];
    const float* b_mean = (const float*)d_in[20];
    const float* W_logv = (const float*)d_in[21];
    const float* b_logv = (const float*)d_in[22];
    const float* W_l2h  = (const float*)d_in[23];
    const float* b_l2h  = (const float*)d_in[24];
    const float* W_out  = (const float*)d_in[25];
    const float* b_out  = (const float*)d_in[26];
    const float* enc_init = (const float*)d_in[27];
    const float* eps    = (const float*)d_in[28];

    float* out      = (float*)d_out;
    float* out_mean = out + (size_t)TT * DD * VV;
    float* out_logv = out_mean + DD * ZZ;
    float* out_z    = out_logv + DD * ZZ;
    float* gi       = out;                  // scratch in logits region: [4096][3072]

    char* ws = (char*)d_ws;
    float*          hb0     = (float*)(ws + 0);                  // 128KB
    float*          hb1     = (float*)(ws + 131072);             // 128KB
    __hip_bfloat16* outs_bf = (__hip_bfloat16*)(ws + 262144);    // 2MB
    __hip_bfloat16* A_bf    = (__hip_bfloat16*)(ws + 2359296);   // 2MB
    __hip_bfloat16* Wb      = (__hip_bfloat16*)(ws + 4456448);   // 16MB
    __hip_bfloat16* B_all   = (__hip_bfloat16*)(ws + 20840448);  // 1.5MB [3072][256]
    float*          pm      = (float*)(ws + 22413312);           // 800KB
    float*          ps      = (float*)(ws + 23437312);           // 800KB
    float*          lse     = (float*)(ws + 24461312);           // 16KB
    unsigned char*  ecan    = (unsigned char*)(ws + 24477696);   // 4KB

    edge_canon_k<<<1, 256, 0, stream>>>(edges_raw, ecan);
    conv_bf16<<<2048, 256, 0, stream>>>(W_out, Wb, VV * HH);
    conv_bf16<<<192, 256, 0, stream>>>(ecWih, B_all + 0 * 768 * HH, 768 * HH);
    conv_bf16<<<192, 256, 0, stream>>>(esWih, B_all + 1 * 768 * HH, 768 * HH);
    conv_bf16<<<192, 256, 0, stream>>>(dcWih, B_all + 2 * 768 * HH, 768 * HH);
    conv_bf16<<<192, 256, 0, stream>>>(dsWih, B_all + 3 * 768 * HH, 768 * HH);
    gather_a<<<1024, 256, 0, stream>>>(nodes, emb, A_bf);

    // gi[4096][3072] = A_bf x B_all^T  (into d_out scratch); 6 slabs x 8 chunks
    gemm_rs<true, false, false, false><<<dim3(64, 6), 256, 0, stream>>>(
        A_bf, B_all, 3072, 8, 6, nullptr, nullptr, gi, nullptr, nullptr);

    // encoder
    for (int t = 0; t < TT; ++t) {
        const float* hin = (t == 0) ? enc_init : ((t & 1) ? hb0 : hb1);
        float* hout = (t & 1) ? hb1 : hb0;
        gru_step3<<<dim3(8, 128), 256, 0, stream>>>(
            ecan + t * DD, gi + (size_t)t * DD * 3072, 0,
            ecWhh, ecbih, ecbhh, esWhh, esbih, esbhh,
            hin, hout, (__hip_bfloat16*)nullptr);
    }
    latent_k<<<128, 256, 0, stream>>>(hb1, W_mean, b_mean, W_logv, b_logv, eps,
                                      out_mean, out_logv, out_z);
    h0_k<<<128, 256, 0, stream>>>(out_z, W_l2h, b_l2h, hb0);

    // decoder
    for (int t = 0; t < TT; ++t) {
        const float* hin = (t & 1) ? hb1 : hb0;
        float* hout = (t & 1) ? hb0 : hb1;
        gru_step3<<<dim3(8, 128), 256, 0, stream>>>(
            ecan + t * DD, gi + (size_t)t * DD * 3072, 1536,
            dcWhh, dcbih, dcbhh, dsWhh, dsbih, dsbhh,
            hin, hout, outs_bf + (size_t)t * DD * HH);
    }

    // pass A: LSE partials only (no C write)
    gemm_rs<false, true, true, false><<<dim3(64, NTL), 256, 0, stream>>>(
        outs_bf, Wb, VV, 10, NTL, b_out, nullptr, nullptr, pm, ps);
    lse_reduce<<<4096, 64, 0, stream>>>(pm, ps, lse, NTL);
    // pass B: recompute, write logp = logits - lse
    gemm_rs<true, true, false, true><<<dim3(64, NTL), 256, 0, stream>>>(
        outs_bf, Wb, VV, 10, NTL, b_out, lse, out, nullptr, nullptr);
}